// Round 2
// baseline (205.325 us; speedup 1.0000x reference)
//
#include <hip/hip_runtime.h>

// Problem geometry
#define NB   16
#define C0   128
#define HH   44
#define WW   144
#define HW   (HH * WW)        // 6336
#define NPOS (NB * HW)        // 101376
#define SC   8
#define WOUT (WW * SC)        // 1152
#define HOUT (HH * SC)        // 352
#define PI_F 3.1415926535f

__device__ __forceinline__ float eluf(float x) {
    return x > 0.f ? x : (__expf(x) - 1.f);
}
__device__ __forceinline__ float sigmoidf(float x) {
    return 1.f / (1.f + __expf(-x));
}

// Fully fused: 1x1-conv chain (128->64->32->16->8->4->3, ELU between) +
// plane-parameter math + 8x8 repeat-interleave upsample with per-pixel depth.
// One thread per low-res position. All weights are wave-uniform (compile-time
// offsets from kernel args -> scalar loads); activations fully unrolled so
// they stay in VGPRs. x loads are coalesced (lane = consecutive hw) and
// double-buffered in 8-channel chunks to hide HBM latency at low occupancy.
__global__ __launch_bounds__(64, 2)
void lpg_fused(const float* __restrict__ x,
               const float* __restrict__ w0, const float* __restrict__ b0,
               const float* __restrict__ w1, const float* __restrict__ b1,
               const float* __restrict__ w2, const float* __restrict__ b2,
               const float* __restrict__ w3, const float* __restrict__ b3,
               const float* __restrict__ w4, const float* __restrict__ b4,
               const float* __restrict__ wc, const float* __restrict__ bc,
               float* __restrict__ out) {
    const int p  = blockIdx.x * 64 + (int)threadIdx.x;   // NPOS % 64 == 0
    const int b  = p / HW;
    const int hw = p - b * HW;
    const float* xp = x + (size_t)b * (C0 * HW) + hw;    // + c*HW walks channels

    // ---- conv0: 128 -> 64 ----
    float h1[64];
#pragma unroll
    for (int o = 0; o < 64; ++o) h1[o] = b0[o];

    float xv[8], xn[8];
#pragma unroll
    for (int j = 0; j < 8; ++j) xv[j] = xp[j * HW];

    for (int c0 = 0; c0 < 128; c0 += 8) {
        const bool more = (c0 + 8) < 128;
        if (more) {
#pragma unroll
            for (int j = 0; j < 8; ++j) xn[j] = xp[(c0 + 8 + j) * HW];
        }
        const float* w = w0 + c0;                        // uniform -> s_load
#pragma unroll
        for (int o = 0; o < 64; ++o) {                   // h1 stays in VGPRs
            float a = h1[o];
#pragma unroll
            for (int j = 0; j < 8; ++j) a = fmaf(xv[j], w[o * 128 + j], a);
            h1[o] = a;
        }
        if (more) {
#pragma unroll
            for (int j = 0; j < 8; ++j) xv[j] = xn[j];
        }
    }
#pragma unroll
    for (int o = 0; o < 64; ++o) h1[o] = eluf(h1[o]);

    // ---- conv1: 64 -> 32 ----
    float h2[32];
#pragma unroll
    for (int o = 0; o < 32; ++o) {
        float a = b1[o];
#pragma unroll
        for (int c = 0; c < 64; ++c) a = fmaf(h1[c], w1[o * 64 + c], a);
        h2[o] = eluf(a);
    }

    // ---- conv2: 32 -> 16 ----
    float h3[16];
#pragma unroll
    for (int o = 0; o < 16; ++o) {
        float a = b2[o];
#pragma unroll
        for (int c = 0; c < 32; ++c) a = fmaf(h2[c], w2[o * 32 + c], a);
        h3[o] = eluf(a);
    }

    // ---- conv3: 16 -> 8 ----
    float h4[8];
#pragma unroll
    for (int o = 0; o < 8; ++o) {
        float a = b3[o];
#pragma unroll
        for (int c = 0; c < 16; ++c) a = fmaf(h3[c], w3[o * 16 + c], a);
        h4[o] = eluf(a);
    }

    // ---- conv4: 8 -> 4 (no activation) ----
    float h5[4];
#pragma unroll
    for (int o = 0; o < 4; ++o) {
        float a = b4[o];
#pragma unroll
        for (int c = 0; c < 8; ++c) a = fmaf(h4[c], w4[o * 8 + c], a);
        h5[o] = a;
    }

    // ---- convc: 4 -> 3 ----
    float y0 = bc[0], y1 = bc[1], y2 = bc[2];
#pragma unroll
    for (int c = 0; c < 4; ++c) {
        y0 = fmaf(h5[c], wc[0 * 4 + c], y0);
        y1 = fmaf(h5[c], wc[1 * 4 + c], y1);
        y2 = fmaf(h5[c], wc[2 * 4 + c], y2);
    }

    // ---- plane parameters ----
    const float theta = sigmoidf(y0) * (PI_F / 6.0f);
    const float phi   = sigmoidf(y1) * (PI_F * 2.0f);
    const float dist  = sigmoidf(y2) * 81.0f;

    const float st = __sinf(theta), ct = __cosf(theta);
    const float sp = __sinf(phi),   cp = __cosf(phi);
    float nx = st * cp, ny = st * sp, nz = ct;
    const float inv = rsqrtf(fmaxf(nx * nx + ny * ny + nz * nz, 1e-24f));
    nx *= inv; ny *= inv; nz *= inv;

    // ---- 8x8 upsample + per-pixel depth ----
    const int h = hw / WW;
    const int w = hw - h * WW;
    float* op = out + ((size_t)b * HOUT + (size_t)h * SC) * WOUT + (size_t)w * SC;

    float nxu[8];
#pragma unroll
    for (int j = 0; j < 8; ++j) nxu[j] = nx * ((j - 3.5f) * 0.125f);

#pragma unroll
    for (int i = 0; i < 8; ++i) {
        const float den0 = fmaf(ny, (i - 3.5f) * 0.125f, nz);
        float d[8];
#pragma unroll
        for (int j = 0; j < 8; ++j)
            d[j] = dist * __builtin_amdgcn_rcpf(den0 + nxu[j]);
        float4 v0 = make_float4(d[0], d[1], d[2], d[3]);
        float4 v1 = make_float4(d[4], d[5], d[6], d[7]);
        float* row = op + (size_t)i * WOUT;              // 16B aligned
        *reinterpret_cast<float4*>(row)     = v0;
        *reinterpret_cast<float4*>(row + 4) = v1;
    }
}

extern "C" void kernel_launch(void* const* d_in, const int* in_sizes, int n_in,
                              void* d_out, int out_size, void* d_ws, size_t ws_size,
                              hipStream_t stream) {
    const float* x  = (const float*)d_in[0];
    const float* w0 = (const float*)d_in[1];  const float* b0 = (const float*)d_in[2];
    const float* w1 = (const float*)d_in[3];  const float* b1 = (const float*)d_in[4];
    const float* w2 = (const float*)d_in[5];  const float* b2 = (const float*)d_in[6];
    const float* w3 = (const float*)d_in[7];  const float* b3 = (const float*)d_in[8];
    const float* w4 = (const float*)d_in[9];  const float* b4 = (const float*)d_in[10];
    const float* wc = (const float*)d_in[11]; const float* bc = (const float*)d_in[12];
    float* out = (float*)d_out;

    hipLaunchKernelGGL(lpg_fused, dim3(NPOS / 64), dim3(64), 0, stream,
                       x, w0, b0, w1, b1, w2, b2, w3, b3, w4, b4, wc, bc, out);
}

// Round 3
// 170.040 us; speedup vs baseline: 1.2075x; 1.2075x over previous
//
#include <hip/hip_runtime.h>

// Problem geometry
#define NB   16
#define C0   128
#define HH   44
#define WW   144
#define HW   (HH * WW)        // 6336
#define NPOS (NB * HW)        // 101376
#define SC   8
#define WOUT (WW * SC)        // 1152
#define HOUT (HH * SC)        // 352
#define PI_F 3.1415926535f

// transposed-weight layout in ws (float elements): wT[c][o]
#define T0 0        // 128 x 64
#define T1 8192     // 64 x 32
#define T2 10240    // 32 x 16
#define T3 10752    // 16 x 8
#define T4 10880    // 8 x 4
#define NWT 10912

__device__ __forceinline__ float eluf(float x) {
    return x > 0.f ? x : (__expf(x) - 1.f);
}
__device__ __forceinline__ float sigmoidf(float x) {
    return 1.f / (1.f + __expf(-x));
}

// ---- prep: transpose the 5 conv weight matrices into ws as wT[c][o] ----
__global__ void prep_w(const float* __restrict__ w0, const float* __restrict__ w1,
                       const float* __restrict__ w2, const float* __restrict__ w3,
                       const float* __restrict__ w4, float* __restrict__ ws) {
    int i = blockIdx.x * 256 + threadIdx.x;
    if (i < 8192)                { int c = i >> 6, o = i & 63; ws[T0 + i] = w0[o * 128 + c]; return; }
    if ((i -= 8192) < 2048)      { int c = i >> 5, o = i & 31; ws[T1 + i] = w1[o * 64 + c];  return; }
    if ((i -= 2048) < 512)       { int c = i >> 4, o = i & 15; ws[T2 + i] = w2[o * 32 + c];  return; }
    if ((i -= 512) < 128)        { int c = i >> 3, o = i & 7;  ws[T3 + i] = w3[o * 16 + c];  return; }
    if ((i -= 128) < 32)         { int c = i >> 2, o = i & 3;  ws[T4 + i] = w4[o * 8 + c];   return; }
}

// ---- main: block = 256 threads (4 waves) handles 256 positions ----
// conv0: M=4 positions/thread, N-split: wave w computes outs [16w,16w+16).
// x staged through LDS in 8-channel double-buffered chunks; inter-layer
// activations passed through LDS [out][pos] (b128 reads/writes); weights
// read as s_load_dwordx16 from the transposed ws (1 scalar : 4 FMAs).
__global__ __launch_bounds__(256, 2)
void lpg_main(const float* __restrict__ x, const float* __restrict__ ws,
              const float* __restrict__ b0, const float* __restrict__ b1,
              const float* __restrict__ b2, const float* __restrict__ b3,
              const float* __restrict__ b4,
              const float* __restrict__ wc, const float* __restrict__ bc,
              float* __restrict__ out) {
    __shared__ float smem[16384];   // 64 KB; regions nested per phase
    const int tid  = (int)threadIdx.x;
    const int lane = tid & 63;
    const int wid  = tid >> 6;      // 0..3
    const int P0   = blockIdx.x * 256;

    // thread tid <-> position P0+tid (staging loads + epilogue)
    const int pt  = P0 + tid;
    const int bt  = pt / HW;
    const int hwt = pt - bt * HW;
    const float* xpt = x + (size_t)bt * (C0 * HW) + hwt;

    // ---- conv0: 128 -> 64 ----
    const int ob0 = wid * 16;
    float acc[16][4];
#pragma unroll
    for (int o = 0; o < 16; ++o) {
        float bb = b0[ob0 + o];
        acc[o][0] = bb; acc[o][1] = bb; acc[o][2] = bb; acc[o][3] = bb;
    }

    float xr[8];
#pragma unroll
    for (int j = 0; j < 8; ++j) xr[j] = xpt[j * HW];
#pragma unroll
    for (int j = 0; j < 8; ++j) smem[j * 256 + tid] = xr[j];
    __syncthreads();

    for (int k = 0; k < 16; ++k) {
        if (k < 15) {
#pragma unroll
            for (int j = 0; j < 8; ++j) xr[j] = xpt[((k + 1) * 8 + j) * HW];
        }
        const float* xs = smem + (k & 1) * 2048;
        const float* wT = ws + T0 + (k * 8) * 64 + ob0;   // wT0[c][o], 16 consecutive o
#pragma unroll
        for (int c = 0; c < 8; ++c) {
            const float4 xv = *reinterpret_cast<const float4*>(xs + c * 256 + 4 * lane);
#pragma unroll
            for (int o = 0; o < 16; ++o) {
                const float wv = wT[c * 64 + o];
                acc[o][0] = fmaf(xv.x, wv, acc[o][0]);
                acc[o][1] = fmaf(xv.y, wv, acc[o][1]);
                acc[o][2] = fmaf(xv.z, wv, acc[o][2]);
                acc[o][3] = fmaf(xv.w, wv, acc[o][3]);
            }
        }
        if (k < 15) {
            float* xsn = smem + ((k + 1) & 1) * 2048;     // not read this iter
#pragma unroll
            for (int j = 0; j < 8; ++j) xsn[j * 256 + tid] = xr[j];
        }
        __syncthreads();
    }

    // ELU + write h1[o][pos] into smem[0..16384)
#pragma unroll
    for (int o = 0; o < 16; ++o) {
        float4 v = make_float4(eluf(acc[o][0]), eluf(acc[o][1]), eluf(acc[o][2]), eluf(acc[o][3]));
        *reinterpret_cast<float4*>(smem + (ob0 + o) * 256 + 4 * lane) = v;
    }
    __syncthreads();

    // ---- conv1: 64 -> 32 (wave computes 8 outs) ----
    const int ob1 = wid * 8;
    float a1[8][4];
#pragma unroll
    for (int o = 0; o < 8; ++o) {
        float bb = b1[ob1 + o];
        a1[o][0] = bb; a1[o][1] = bb; a1[o][2] = bb; a1[o][3] = bb;
    }
    for (int c = 0; c < 64; ++c) {
        const float4 xv = *reinterpret_cast<const float4*>(smem + c * 256 + 4 * lane);
        const float* wT = ws + T1 + c * 32 + ob1;
#pragma unroll
        for (int o = 0; o < 8; ++o) {
            const float wv = wT[o];
            a1[o][0] = fmaf(xv.x, wv, a1[o][0]);
            a1[o][1] = fmaf(xv.y, wv, a1[o][1]);
            a1[o][2] = fmaf(xv.z, wv, a1[o][2]);
            a1[o][3] = fmaf(xv.w, wv, a1[o][3]);
        }
    }
    __syncthreads();   // all h1 reads done before overwriting
#pragma unroll
    for (int o = 0; o < 8; ++o) {
        float4 v = make_float4(eluf(a1[o][0]), eluf(a1[o][1]), eluf(a1[o][2]), eluf(a1[o][3]));
        *reinterpret_cast<float4*>(smem + (ob1 + o) * 256 + 4 * lane) = v;
    }
    __syncthreads();

    // ---- conv2: 32 -> 16 (wave computes 4 outs) ----
    const int ob2 = wid * 4;
    float a2[4][4];
#pragma unroll
    for (int o = 0; o < 4; ++o) {
        float bb = b2[ob2 + o];
        a2[o][0] = bb; a2[o][1] = bb; a2[o][2] = bb; a2[o][3] = bb;
    }
    for (int c = 0; c < 32; ++c) {
        const float4 xv = *reinterpret_cast<const float4*>(smem + c * 256 + 4 * lane);
        const float* wT = ws + T2 + c * 16 + ob2;
#pragma unroll
        for (int o = 0; o < 4; ++o) {
            const float wv = wT[o];
            a2[o][0] = fmaf(xv.x, wv, a2[o][0]);
            a2[o][1] = fmaf(xv.y, wv, a2[o][1]);
            a2[o][2] = fmaf(xv.z, wv, a2[o][2]);
            a2[o][3] = fmaf(xv.w, wv, a2[o][3]);
        }
    }
    __syncthreads();
#pragma unroll
    for (int o = 0; o < 4; ++o) {
        float4 v = make_float4(eluf(a2[o][0]), eluf(a2[o][1]), eluf(a2[o][2]), eluf(a2[o][3]));
        *reinterpret_cast<float4*>(smem + (ob2 + o) * 256 + 4 * lane) = v;
    }
    __syncthreads();

    // ---- conv3: 16 -> 8 (wave computes 2 outs) ----
    const int ob3 = wid * 2;
    float a3[2][4];
#pragma unroll
    for (int o = 0; o < 2; ++o) {
        float bb = b3[ob3 + o];
        a3[o][0] = bb; a3[o][1] = bb; a3[o][2] = bb; a3[o][3] = bb;
    }
    for (int c = 0; c < 16; ++c) {
        const float4 xv = *reinterpret_cast<const float4*>(smem + c * 256 + 4 * lane);
        const float* wT = ws + T3 + c * 8 + ob3;
#pragma unroll
        for (int o = 0; o < 2; ++o) {
            const float wv = wT[o];
            a3[o][0] = fmaf(xv.x, wv, a3[o][0]);
            a3[o][1] = fmaf(xv.y, wv, a3[o][1]);
            a3[o][2] = fmaf(xv.z, wv, a3[o][2]);
            a3[o][3] = fmaf(xv.w, wv, a3[o][3]);
        }
    }
    __syncthreads();
#pragma unroll
    for (int o = 0; o < 2; ++o) {
        float4 v = make_float4(eluf(a3[o][0]), eluf(a3[o][1]), eluf(a3[o][2]), eluf(a3[o][3]));
        *reinterpret_cast<float4*>(smem + (ob3 + o) * 256 + 4 * lane) = v;
    }
    __syncthreads();

    // ---- conv4: 8 -> 4 (wave computes 1 out, NO activation) ----
    float a4[4];
    {
        float bb = b4[wid];
        a4[0] = bb; a4[1] = bb; a4[2] = bb; a4[3] = bb;
        for (int c = 0; c < 8; ++c) {
            const float4 xv = *reinterpret_cast<const float4*>(smem + c * 256 + 4 * lane);
            const float wv = ws[T4 + c * 4 + wid];
            a4[0] = fmaf(xv.x, wv, a4[0]);
            a4[1] = fmaf(xv.y, wv, a4[1]);
            a4[2] = fmaf(xv.z, wv, a4[2]);
            a4[3] = fmaf(xv.w, wv, a4[3]);
        }
    }
    __syncthreads();
    // h5 as [pos][4] for b128 reads in epilogue
#pragma unroll
    for (int p = 0; p < 4; ++p) smem[(4 * lane + p) * 4 + wid] = a4[p];
    __syncthreads();

    // ---- convc (4->3) + plane params + 8x8 upsample: thread = one position ----
    const float4 h5 = *reinterpret_cast<const float4*>(smem + tid * 4);
    float y0 = bc[0], y1 = bc[1], y2 = bc[2];
    y0 = fmaf(h5.x, wc[0], fmaf(h5.y, wc[1], fmaf(h5.z, wc[2], fmaf(h5.w, wc[3], y0))));
    y1 = fmaf(h5.x, wc[4], fmaf(h5.y, wc[5], fmaf(h5.z, wc[6], fmaf(h5.w, wc[7], y1))));
    y2 = fmaf(h5.x, wc[8], fmaf(h5.y, wc[9], fmaf(h5.z, wc[10], fmaf(h5.w, wc[11], y2))));

    const float theta = sigmoidf(y0) * (PI_F / 6.0f);
    const float phi   = sigmoidf(y1) * (PI_F * 2.0f);
    const float dist  = sigmoidf(y2) * 81.0f;

    const float st = __sinf(theta), ct = __cosf(theta);
    const float sp = __sinf(phi),   cp = __cosf(phi);
    float nx = st * cp, ny = st * sp, nz = ct;
    const float inv = rsqrtf(fmaxf(nx * nx + ny * ny + nz * nz, 1e-24f));
    nx *= inv; ny *= inv; nz *= inv;

    const int h = hwt / WW;
    const int w = hwt - h * WW;
    float* op = out + ((size_t)bt * HOUT + (size_t)h * SC) * WOUT + (size_t)w * SC;

    float nxu[8];
#pragma unroll
    for (int j = 0; j < 8; ++j) nxu[j] = nx * ((j - 3.5f) * 0.125f);

#pragma unroll
    for (int i = 0; i < 8; ++i) {
        const float den0 = fmaf(ny, (i - 3.5f) * 0.125f, nz);
        float d[8];
#pragma unroll
        for (int j = 0; j < 8; ++j)
            d[j] = dist * __builtin_amdgcn_rcpf(den0 + nxu[j]);
        float* row = op + (size_t)i * WOUT;               // 32B-aligned
        *reinterpret_cast<float4*>(row)     = make_float4(d[0], d[1], d[2], d[3]);
        *reinterpret_cast<float4*>(row + 4) = make_float4(d[4], d[5], d[6], d[7]);
    }
}

extern "C" void kernel_launch(void* const* d_in, const int* in_sizes, int n_in,
                              void* d_out, int out_size, void* d_ws, size_t ws_size,
                              hipStream_t stream) {
    const float* x  = (const float*)d_in[0];
    const float* w0 = (const float*)d_in[1];  const float* b0 = (const float*)d_in[2];
    const float* w1 = (const float*)d_in[3];  const float* b1 = (const float*)d_in[4];
    const float* w2 = (const float*)d_in[5];  const float* b2 = (const float*)d_in[6];
    const float* w3 = (const float*)d_in[7];  const float* b3 = (const float*)d_in[8];
    const float* w4 = (const float*)d_in[9];  const float* b4 = (const float*)d_in[10];
    const float* wc = (const float*)d_in[11]; const float* bc = (const float*)d_in[12];
    float* ws  = (float*)d_ws;                // 43,648 B used
    float* out = (float*)d_out;

    hipLaunchKernelGGL(prep_w, dim3((NWT + 255) / 256), dim3(256), 0, stream,
                       w0, w1, w2, w3, w4, ws);
    hipLaunchKernelGGL(lpg_main, dim3(NPOS / 256), dim3(256), 0, stream,
                       x, ws, b0, b1, b2, b3, b4, wc, bc, out);
}

// Round 4
// 123.627 us; speedup vs baseline: 1.6608x; 1.3754x over previous
//
#include <hip/hip_runtime.h>

// Problem geometry
#define NB   16
#define C0   128
#define HH   44
#define WW   144
#define HW   (HH * WW)        // 6336
#define NPOS (NB * HW)        // 101376
#define SC   8
#define WOUT (WW * SC)        // 1152
#define HOUT (HH * SC)        // 352
#define PI_F 3.1415926535f

typedef __attribute__((ext_vector_type(8))) short bf8;   // 8 bf16 (A/B frag)
typedef __attribute__((ext_vector_type(4))) float f4;    // 4 fp32 (C/D frag)

__device__ __forceinline__ unsigned short f2bf(float f) {
    union { float f; unsigned u; } v; v.f = f;
    unsigned r = v.u + 0x7FFFu + ((v.u >> 16) & 1u);     // RNE
    return (unsigned short)(r >> 16);
}
__device__ __forceinline__ float eluf(float x) {
    return x > 0.f ? x : (__expf(x) - 1.f);
}
__device__ __forceinline__ float sigmoidf(float x) {
    return 1.f / (1.f + __expf(-x));
}

// LDS ushort offsets (all row strides keep 16B alignment, +8 pad kills bank conflicts)
#define W0B 0        // [64][136]  (128 ch + 8 pad)
#define W1B 8704     // [32][72]
#define W2B 11008    // [16][40]
#define WSM_N 11648  // 23,296 B
// per-wave activation buffer (2432 ushorts = 4864 B, 16B-aligned rows)
#define H1B 0        // bf16 [16 pos][72]   (64 ch + 8 pad)
#define H2B 1152     // bf16 [16 pos][40]   (32 ch + 8 pad)
#define H3F 1792     // fp32 [16 pos][20]   (16 ch + 4 pad)  (ushort offset; /2 floats)

// One wave = 16 positions. conv0/1/2 via bf16 MFMA 16x16x32 (B consumed as
// B^T = w[out][ch], the verified gemm_bt pattern). Inter-layer transpose via
// wave-private LDS round-trip (C-layout scatter -> A-layout b128 reads).
// conv3/4/c + plane math + 8x8 upsample in VALU, redundant per quad.
// Single barrier (weight staging); everything else wave-local.
__global__ __launch_bounds__(256, 3)
void lpg_mfma(const float* __restrict__ x,
              const float* __restrict__ w0, const float* __restrict__ b0,
              const float* __restrict__ w1, const float* __restrict__ b1,
              const float* __restrict__ w2, const float* __restrict__ b2,
              const float* __restrict__ w3, const float* __restrict__ b3,
              const float* __restrict__ w4, const float* __restrict__ b4,
              const float* __restrict__ wc, const float* __restrict__ bc,
              float* __restrict__ out) {
    __shared__ __align__(16) unsigned short wsm[WSM_N];
    __shared__ __align__(16) unsigned short hbuf[4][2432];

    const int tid  = (int)threadIdx.x;
    const int lane = tid & 63;
    const int wid  = tid >> 6;
    const int q    = lane >> 4;          // quad 0..3
    const int n    = lane & 15;          // col index / A-row (position) index

    const int p0 = blockIdx.x * 64 + wid * 16;   // wave's position base
    const int pm = p0 + n;                        // this lane's position
    const int bm = pm / HW;
    const int hwm = pm - bm * HW;

    // ---- issue all x loads early (A operand, fp32 -> bf16 later) ----
    // A[m=n][k=8q+j+32kk]: per instr, 4 quads x 16 consecutive pos = 4x64B segs
    const float* xb = x + (size_t)bm * (C0 * HW) + hwm;
    float xr[32];
#pragma unroll
    for (int kk = 0; kk < 4; ++kk)
#pragma unroll
        for (int j = 0; j < 8; ++j)
            xr[kk * 8 + j] = xb[(kk * 32 + q * 8 + j) * HW];

    // ---- stage weights to LDS as bf16 (coalesced reads, ~2-way bank writes) ----
#pragma unroll
    for (int k = 0; k < 32; ++k) { int i = tid + 256 * k; int o = i >> 7, c = i & 127; wsm[W0B + o * 136 + c] = f2bf(w0[i]); }
#pragma unroll
    for (int k = 0; k < 8; ++k)  { int i = tid + 256 * k; int o = i >> 6, c = i & 63;  wsm[W1B + o * 72  + c] = f2bf(w1[i]); }
#pragma unroll
    for (int k = 0; k < 2; ++k)  { int i = tid + 256 * k; int o = i >> 5, c = i & 31;  wsm[W2B + o * 40  + c] = f2bf(w2[i]); }
    __syncthreads();

    // ---- pack A fragments ----
    bf8 A[4];
#pragma unroll
    for (int kk = 0; kk < 4; ++kk) {
        bf8 a;
#pragma unroll
        for (int j = 0; j < 8; ++j) a[j] = (short)f2bf(xr[kk * 8 + j]);
        A[kk] = a;
    }

    // ---- conv0: 128 -> 64, 4 N-tiles x 4 K-steps = 16 MFMA ----
    f4 acc[4];
#pragma unroll
    for (int t = 0; t < 4; ++t) acc[t] = (f4){0.f, 0.f, 0.f, 0.f};
#pragma unroll
    for (int t = 0; t < 4; ++t) {
        bf8 B[4];
#pragma unroll
        for (int kk = 0; kk < 4; ++kk)
            B[kk] = *(const bf8*)(wsm + W0B + (t * 16 + n) * 136 + kk * 32 + q * 8);
#pragma unroll
        for (int kk = 0; kk < 4; ++kk)
            acc[t] = __builtin_amdgcn_mfma_f32_16x16x32_bf16(A[kk], B[kk], acc[t], 0, 0, 0);
    }

    // bias + ELU, write C-layout (pos=4q+r, out=16t+n) -> h1b[pos][out] bf16
    unsigned short* hb = &hbuf[wid][0];
#pragma unroll
    for (int t = 0; t < 4; ++t) {
        const float bb = b0[t * 16 + n];
#pragma unroll
        for (int r = 0; r < 4; ++r)
            hb[H1B + (q * 4 + r) * 72 + t * 16 + n] = f2bf(eluf(acc[t][r] + bb));
    }

    // ---- conv1: 64 -> 32, 2 N-tiles x 2 K-steps ----
    bf8 A1[2];
#pragma unroll
    for (int kk = 0; kk < 2; ++kk)
        A1[kk] = *(const bf8*)(hb + H1B + n * 72 + kk * 32 + q * 8);
    f4 acc1[2];
#pragma unroll
    for (int t = 0; t < 2; ++t) acc1[t] = (f4){0.f, 0.f, 0.f, 0.f};
#pragma unroll
    for (int t = 0; t < 2; ++t)
#pragma unroll
        for (int kk = 0; kk < 2; ++kk) {
            bf8 B = *(const bf8*)(wsm + W1B + (t * 16 + n) * 72 + kk * 32 + q * 8);
            acc1[t] = __builtin_amdgcn_mfma_f32_16x16x32_bf16(A1[kk], B, acc1[t], 0, 0, 0);
        }
#pragma unroll
    for (int t = 0; t < 2; ++t) {
        const float bb = b1[t * 16 + n];
#pragma unroll
        for (int r = 0; r < 4; ++r)
            hb[H2B + (q * 4 + r) * 40 + t * 16 + n] = f2bf(eluf(acc1[t][r] + bb));
    }

    // ---- conv2: 32 -> 16, single MFMA ----
    bf8 A2 = *(const bf8*)(hb + H2B + n * 40 + q * 8);
    bf8 B2 = *(const bf8*)(wsm + W2B + n * 40 + q * 8);
    f4 acc2 = (f4){0.f, 0.f, 0.f, 0.f};
    acc2 = __builtin_amdgcn_mfma_f32_16x16x32_bf16(A2, B2, acc2, 0, 0, 0);
    float* h3f = (float*)(hb + H3F);
    {
        const float bb = b2[n];
#pragma unroll
        for (int r = 0; r < 4; ++r)
            h3f[(q * 4 + r) * 20 + n] = eluf(acc2[r] + bb);
    }

    // ---- tail: lane handles pos=n (redundant across quads, broadcast reads) ----
    float h3[16];
#pragma unroll
    for (int i = 0; i < 4; ++i) {
        f4 v = *(const f4*)(h3f + n * 20 + i * 4);
        h3[4 * i + 0] = v[0]; h3[4 * i + 1] = v[1];
        h3[4 * i + 2] = v[2]; h3[4 * i + 3] = v[3];
    }

    float h4v[8];
#pragma unroll
    for (int o = 0; o < 8; ++o) {
        float a = b3[o];                              // uniform -> s_load
#pragma unroll
        for (int c = 0; c < 16; ++c) a = fmaf(h3[c], w3[o * 16 + c], a);
        h4v[o] = eluf(a);
    }
    float h5v[4];
#pragma unroll
    for (int o = 0; o < 4; ++o) {
        float a = b4[o];
#pragma unroll
        for (int c = 0; c < 8; ++c) a = fmaf(h4v[c], w4[o * 8 + c], a);
        h5v[o] = a;                                   // no activation
    }
    float y0 = bc[0], y1 = bc[1], y2 = bc[2];
#pragma unroll
    for (int c = 0; c < 4; ++c) {
        y0 = fmaf(h5v[c], wc[0 * 4 + c], y0);
        y1 = fmaf(h5v[c], wc[1 * 4 + c], y1);
        y2 = fmaf(h5v[c], wc[2 * 4 + c], y2);
    }

    const float theta = sigmoidf(y0) * (PI_F / 6.0f);
    const float phi   = sigmoidf(y1) * (PI_F * 2.0f);
    const float dist  = sigmoidf(y2) * 81.0f;
    const float st = __sinf(theta), ct = __cosf(theta);
    const float sp = __sinf(phi),   cp = __cosf(phi);
    float nx = st * cp, ny = st * sp, nz = ct;
    const float inv = rsqrtf(fmaxf(nx * nx + ny * ny + nz * nz, 1e-24f));
    nx *= inv; ny *= inv; nz *= inv;

    // ---- 8x8 upsample: quad q writes rows 2q, 2q+1 of its position ----
    const int hh = hwm / WW;
    const int wp = hwm - hh * WW;
    float* op = out + ((size_t)bm * HOUT + (size_t)hh * SC) * WOUT + (size_t)wp * SC;

    float nxu[8];
#pragma unroll
    for (int j = 0; j < 8; ++j) nxu[j] = nx * ((j - 3.5f) * 0.125f);

#pragma unroll
    for (int ii = 0; ii < 2; ++ii) {
        const int i = q * 2 + ii;
        const float den0 = fmaf(ny, (i - 3.5f) * 0.125f, nz);
        float d[8];
#pragma unroll
        for (int j = 0; j < 8; ++j)
            d[j] = dist * __builtin_amdgcn_rcpf(den0 + nxu[j]);
        float* row = op + (size_t)i * WOUT;           // 32B-aligned
        *reinterpret_cast<float4*>(row)     = make_float4(d[0], d[1], d[2], d[3]);
        *reinterpret_cast<float4*>(row + 4) = make_float4(d[4], d[5], d[6], d[7]);
    }
}

extern "C" void kernel_launch(void* const* d_in, const int* in_sizes, int n_in,
                              void* d_out, int out_size, void* d_ws, size_t ws_size,
                              hipStream_t stream) {
    const float* x  = (const float*)d_in[0];
    const float* w0 = (const float*)d_in[1];  const float* b0 = (const float*)d_in[2];
    const float* w1 = (const float*)d_in[3];  const float* b1 = (const float*)d_in[4];
    const float* w2 = (const float*)d_in[5];  const float* b2 = (const float*)d_in[6];
    const float* w3 = (const float*)d_in[7];  const float* b3 = (const float*)d_in[8];
    const float* w4 = (const float*)d_in[9];  const float* b4 = (const float*)d_in[10];
    const float* wc = (const float*)d_in[11]; const float* bc = (const float*)d_in[12];
    float* out = (float*)d_out;

    hipLaunchKernelGGL(lpg_mfma, dim3(NPOS / 64), dim3(256), 0, stream,
                       x, w0, b0, w1, b1, w2, b2, w3, b3, w4, b4, wc, bc, out);
}

// Round 5
// 122.576 us; speedup vs baseline: 1.6751x; 1.0086x over previous
//
#include <hip/hip_runtime.h>
#include <hip/hip_bf16.h>

// Problem geometry
#define NB   16
#define C0   128
#define HH   44
#define WW   144
#define HW   (HH * WW)        // 6336
#define NPOS (NB * HW)        // 101376
#define SC   8
#define WOUT (WW * SC)        // 1152
#define HOUT (HH * SC)        // 352
#define PI_F 3.1415926535f

typedef __attribute__((ext_vector_type(8))) short bf8;   // 8 bf16 (A/B frag)
typedef __attribute__((ext_vector_type(4))) float f4;    // 4 fp32 (C/D frag)
typedef unsigned short ushort_t;

// frag-exact bf16 weight layout in ws (ushort elements):
//   conv0: 16 chunks (t*4+kk) x [64 lanes][8]   -> 8192
//   conv1:  4 chunks (t*2+kk) x [64 lanes][8]   -> 2048
//   conv2:  1 chunk           x [64 lanes][8]   -> 512
#define F0 0
#define F1 8192
#define F2 10240
#define NWT 10752

__device__ __forceinline__ unsigned short f2bf(float f) {
    union { float f; unsigned u; } v; v.f = f;
    unsigned r = v.u + 0x7FFFu + ((v.u >> 16) & 1u);     // RNE
    return (unsigned short)(r >> 16);
}
__device__ __forceinline__ float eluf(float x) {
    return x > 0.f ? x : (__expf(x) - 1.f);
}
__device__ __forceinline__ float sigmoidf(float x) {
    return 1.f / (1.f + __expf(-x));
}

// ---- prep: w0/w1/w2 -> bf16, rearranged so each B-fragment load in the
// main kernel is one fully-coalesced global_load_dwordx4 (lane*16B). ----
__global__ void prep_w(const float* __restrict__ w0, const float* __restrict__ w1,
                       const float* __restrict__ w2, ushort_t* __restrict__ ws) {
    int i = blockIdx.x * 256 + (int)threadIdx.x;
    if (i < 8192) {
        int j = i & 7, lane = (i >> 3) & 63, ch = i >> 9;       // ch = t*4+kk
        int q = lane >> 4, n = lane & 15, kk = ch & 3, t = ch >> 2;
        ws[F0 + i] = f2bf(w0[(t * 16 + n) * 128 + kk * 32 + q * 8 + j]);
    } else if (i < 10240) {
        int i2 = i - 8192;
        int j = i2 & 7, lane = (i2 >> 3) & 63, ch = i2 >> 9;    // ch = t*2+kk
        int q = lane >> 4, n = lane & 15, kk = ch & 1, t = ch >> 1;
        ws[F1 + i2] = f2bf(w1[(t * 16 + n) * 64 + kk * 32 + q * 8 + j]);
    } else if (i < NWT) {
        int i2 = i - 10240;
        int j = i2 & 7, lane = (i2 >> 3) & 63;
        int q = lane >> 4, n = lane & 15;
        ws[F2 + i2] = f2bf(w2[n * 32 + q * 8 + j]);
    }
}

// per-wave activation buffer (2432 ushorts, 16B-aligned rows)
#define H1B 0        // bf16 [16 pos][72]   (64 ch + 8 pad)
#define H2B 1152     // bf16 [16 pos][40]   (32 ch + 8 pad)
#define H3F 1792     // fp32 [16 pos][20]   (16 ch + 4 pad)  (ushort offset; /2 floats)

// One wave = 16 positions. conv0/1/2 via bf16 MFMA 16x16x32; B-frags loaded
// directly from pre-packed global ws (L2-resident) -> NO weight LDS, NO
// barriers. Biases folded into accumulator init (C/D col = lane&15 = channel).
// Inter-layer transpose via wave-private LDS round-trip. conv3/4/c + plane
// math + 8x8 upsample in VALU, redundant per quad (quad q writes rows 2q,2q+1).
__global__ __launch_bounds__(256, 4)
void lpg_mfma(const float* __restrict__ x, const ushort_t* __restrict__ wsb,
              const float* __restrict__ b0, const float* __restrict__ b1,
              const float* __restrict__ b2, const float* __restrict__ b3,
              const float* __restrict__ w3, const float* __restrict__ w4,
              const float* __restrict__ b4,
              const float* __restrict__ wc, const float* __restrict__ bc,
              float* __restrict__ out) {
    __shared__ __align__(16) ushort_t hbuf[4][2432];

    const int tid  = (int)threadIdx.x;
    const int lane = tid & 63;
    const int wid  = tid >> 6;
    const int q    = lane >> 4;          // quad 0..3
    const int n    = lane & 15;          // position-within-tile / out-channel idx

    const int pm = blockIdx.x * 64 + wid * 16 + n;   // this lane's position
    const int bm = pm / HW;
    const int hwm = pm - bm * HW;

    // ---- issue all x loads early (A operand) ----
    // A[m=n][k=kk*32+q*8+j]: per load instr, 4 quads x 16 consecutive pos = 4x64B segs
    const float* xb = x + (size_t)bm * (C0 * HW) + hwm;
    float xr[32];
#pragma unroll
    for (int kk = 0; kk < 4; ++kk)
#pragma unroll
        for (int j = 0; j < 8; ++j)
            xr[kk * 8 + j] = xb[(kk * 32 + q * 8 + j) * HW];

    // ---- pack A fragments (v_cvt_pk_bf16_f32) ----
    bf8 A[4];
#pragma unroll
    for (int kk = 0; kk < 4; ++kk) {
        bf8 a;
#pragma unroll
        for (int j = 0; j < 8; j += 2) {
            __hip_bfloat162 p = __float22bfloat162_rn(
                make_float2(xr[kk * 8 + j], xr[kk * 8 + j + 1]));
            union { __hip_bfloat162 b; short s[2]; } u; u.b = p;
            a[j] = u.s[0]; a[j + 1] = u.s[1];
        }
        A[kk] = a;
    }

    // ---- conv0: 128 -> 64, 4 N-tiles x 4 K-steps = 16 MFMA ----
    f4 acc[4];
#pragma unroll
    for (int t = 0; t < 4; ++t) {
        const float bb = b0[t * 16 + n];
        acc[t] = (f4){bb, bb, bb, bb};
    }
#pragma unroll
    for (int t = 0; t < 4; ++t) {
        bf8 B[4];
#pragma unroll
        for (int kk = 0; kk < 4; ++kk)
            B[kk] = *(const bf8*)(wsb + F0 + (t * 4 + kk) * 512 + lane * 8);
#pragma unroll
        for (int kk = 0; kk < 4; ++kk)
            acc[t] = __builtin_amdgcn_mfma_f32_16x16x32_bf16(A[kk], B[kk], acc[t], 0, 0, 0);
    }

    // ELU, write C-layout (pos=4q+r, out=16t+n) -> h1[pos][out] bf16
    ushort_t* hb = &hbuf[wid][0];
#pragma unroll
    for (int t = 0; t < 4; ++t)
#pragma unroll
        for (int r = 0; r < 4; ++r)
            hb[H1B + (q * 4 + r) * 72 + t * 16 + n] = f2bf(eluf(acc[t][r]));

    // ---- conv1: 64 -> 32, 2 N-tiles x 2 K-steps ----
    bf8 A1[2];
#pragma unroll
    for (int kk = 0; kk < 2; ++kk)
        A1[kk] = *(const bf8*)(hb + H1B + n * 72 + kk * 32 + q * 8);
    f4 acc1[2];
#pragma unroll
    for (int t = 0; t < 2; ++t) {
        const float bb = b1[t * 16 + n];
        acc1[t] = (f4){bb, bb, bb, bb};
    }
#pragma unroll
    for (int t = 0; t < 2; ++t)
#pragma unroll
        for (int kk = 0; kk < 2; ++kk) {
            bf8 B = *(const bf8*)(wsb + F1 + (t * 2 + kk) * 512 + lane * 8);
            acc1[t] = __builtin_amdgcn_mfma_f32_16x16x32_bf16(A1[kk], B, acc1[t], 0, 0, 0);
        }
#pragma unroll
    for (int t = 0; t < 2; ++t)
#pragma unroll
        for (int r = 0; r < 4; ++r)
            hb[H2B + (q * 4 + r) * 40 + t * 16 + n] = f2bf(eluf(acc1[t][r]));

    // ---- conv2: 32 -> 16, single MFMA ----
    bf8 A2 = *(const bf8*)(hb + H2B + n * 40 + q * 8);
    bf8 B2 = *(const bf8*)(wsb + F2 + lane * 8);
    const float bb2 = b2[n];
    f4 acc2 = (f4){bb2, bb2, bb2, bb2};
    acc2 = __builtin_amdgcn_mfma_f32_16x16x32_bf16(A2, B2, acc2, 0, 0, 0);
    float* h3f = (float*)(hb + H3F);
#pragma unroll
    for (int r = 0; r < 4; ++r)
        h3f[(q * 4 + r) * 20 + n] = eluf(acc2[r]);

    // ---- tail: lane handles pos=n (redundant across quads, broadcast reads) ----
    float h3[16];
#pragma unroll
    for (int i = 0; i < 4; ++i) {
        f4 v = *(const f4*)(h3f + n * 20 + i * 4);
        h3[4 * i + 0] = v[0]; h3[4 * i + 1] = v[1];
        h3[4 * i + 2] = v[2]; h3[4 * i + 3] = v[3];
    }

    float h4v[8];
#pragma unroll
    for (int o = 0; o < 8; ++o) {
        float a = b3[o];                              // uniform -> s_load
#pragma unroll
        for (int c = 0; c < 16; ++c) a = fmaf(h3[c], w3[o * 16 + c], a);
        h4v[o] = eluf(a);
    }
    float h5v[4];
#pragma unroll
    for (int o = 0; o < 4; ++o) {
        float a = b4[o];
#pragma unroll
        for (int c = 0; c < 8; ++c) a = fmaf(h4v[c], w4[o * 8 + c], a);
        h5v[o] = a;                                   // no activation
    }
    float y0 = bc[0], y1 = bc[1], y2 = bc[2];
#pragma unroll
    for (int c = 0; c < 4; ++c) {
        y0 = fmaf(h5v[c], wc[0 * 4 + c], y0);
        y1 = fmaf(h5v[c], wc[1 * 4 + c], y1);
        y2 = fmaf(h5v[c], wc[2 * 4 + c], y2);
    }

    const float theta = sigmoidf(y0) * (PI_F / 6.0f);
    const float phi   = sigmoidf(y1) * (PI_F * 2.0f);
    const float dist  = sigmoidf(y2) * 81.0f;
    const float st = __sinf(theta), ct = __cosf(theta);
    const float sp = __sinf(phi),   cp = __cosf(phi);
    float nx = st * cp, ny = st * sp, nz = ct;
    const float inv = rsqrtf(fmaxf(nx * nx + ny * ny + nz * nz, 1e-24f));
    nx *= inv; ny *= inv; nz *= inv;

    // ---- 8x8 upsample: quad q writes rows 2q, 2q+1 of its position ----
    const int hh = hwm / WW;
    const int wp = hwm - hh * WW;
    float* op = out + ((size_t)bm * HOUT + (size_t)hh * SC) * WOUT + (size_t)wp * SC;

    float nxu[8];
#pragma unroll
    for (int j = 0; j < 8; ++j) nxu[j] = nx * ((j - 3.5f) * 0.125f);

#pragma unroll
    for (int ii = 0; ii < 2; ++ii) {
        const int i = q * 2 + ii;
        const float den0 = fmaf(ny, (i - 3.5f) * 0.125f, nz);
        float d[8];
#pragma unroll
        for (int j = 0; j < 8; ++j)
            d[j] = dist * __builtin_amdgcn_rcpf(den0 + nxu[j]);
        float* row = op + (size_t)i * WOUT;           // 32B-aligned
        *reinterpret_cast<float4*>(row)     = make_float4(d[0], d[1], d[2], d[3]);
        *reinterpret_cast<float4*>(row + 4) = make_float4(d[4], d[5], d[6], d[7]);
    }
}

extern "C" void kernel_launch(void* const* d_in, const int* in_sizes, int n_in,
                              void* d_out, int out_size, void* d_ws, size_t ws_size,
                              hipStream_t stream) {
    const float* x  = (const float*)d_in[0];
    const float* w0 = (const float*)d_in[1];  const float* b0 = (const float*)d_in[2];
    const float* w1 = (const float*)d_in[3];  const float* b1 = (const float*)d_in[4];
    const float* w2 = (const float*)d_in[5];  const float* b2 = (const float*)d_in[6];
    const float* w3 = (const float*)d_in[7];  const float* b3 = (const float*)d_in[8];
    const float* w4 = (const float*)d_in[9];  const float* b4 = (const float*)d_in[10];
    const float* wc = (const float*)d_in[11]; const float* bc = (const float*)d_in[12];
    ushort_t* ws = (ushort_t*)d_ws;            // 21,504 B used
    float* out = (float*)d_out;

    hipLaunchKernelGGL(prep_w, dim3((NWT + 255) / 256), dim3(256), 0, stream,
                       w0, w1, w2, ws);
    hipLaunchKernelGGL(lpg_mfma, dim3(NPOS / 64), dim3(256), 0, stream,
                       x, ws, b0, b1, b2, b3, w3, w4, b4, wc, bc, out);
}

// Round 6
// 122.293 us; speedup vs baseline: 1.6790x; 1.0023x over previous
//
#include <hip/hip_runtime.h>
#include <hip/hip_bf16.h>

// Problem geometry
#define NB   16
#define C0   128
#define HH   44
#define WW   144
#define HW   (HH * WW)        // 6336
#define NPOS (NB * HW)        // 101376
#define SC   8
#define WOUT (WW * SC)        // 1152
#define HOUT (HH * SC)        // 352
#define PI_F 3.1415926535f

typedef __attribute__((ext_vector_type(8))) short bf8;   // 8 bf16 (A/B frag)
typedef __attribute__((ext_vector_type(4))) float f4;    // 4 fp32 (C/D frag)
typedef unsigned short ushort_t;

// frag-exact bf16 weight layout in ws (ushort elements):
//   conv0: 16 chunks (t*4+kk) x [64 lanes][8]   -> 8192
//   conv1:  4 chunks (t*2+kk) x [64 lanes][8]   -> 2048
//   conv2:  1 chunk           x [64 lanes][8]   -> 512
#define F0 0
#define F1 8192
#define F2 10240
#define NWT 10752

__device__ __forceinline__ unsigned short f2bf(float f) {
    union { float f; unsigned u; } v; v.f = f;
    unsigned r = v.u + 0x7FFFu + ((v.u >> 16) & 1u);     // RNE
    return (unsigned short)(r >> 16);
}
__device__ __forceinline__ float eluf(float x) {
    return x > 0.f ? x : (__expf(x) - 1.f);
}
__device__ __forceinline__ float sigmoidf(float x) {
    return 1.f / (1.f + __expf(-x));
}

// ---- prep: w0/w1/w2 -> bf16, rearranged so each B-fragment load in the
// main kernel is one fully-coalesced global_load_dwordx4 (lane*16B). ----
__global__ void prep_w(const float* __restrict__ w0, const float* __restrict__ w1,
                       const float* __restrict__ w2, ushort_t* __restrict__ ws) {
    int i = blockIdx.x * 256 + (int)threadIdx.x;
    if (i < 8192) {
        int j = i & 7, lane = (i >> 3) & 63, ch = i >> 9;       // ch = t*4+kk
        int q = lane >> 4, n = lane & 15, kk = ch & 3, t = ch >> 2;
        ws[F0 + i] = f2bf(w0[(t * 16 + n) * 128 + kk * 32 + q * 8 + j]);
    } else if (i < 10240) {
        int i2 = i - 8192;
        int j = i2 & 7, lane = (i2 >> 3) & 63, ch = i2 >> 9;    // ch = t*2+kk
        int q = lane >> 4, n = lane & 15, kk = ch & 1, t = ch >> 1;
        ws[F1 + i2] = f2bf(w1[(t * 16 + n) * 64 + kk * 32 + q * 8 + j]);
    } else if (i < NWT) {
        int i2 = i - 10240;
        int j = i2 & 7, lane = (i2 >> 3) & 63;
        int q = lane >> 4, n = lane & 15;
        ws[F2 + i2] = f2bf(w2[n * 32 + q * 8 + j]);
    }
}

// per-wave activation buffer (2432 ushorts, 16B-aligned rows)
#define H1B 0        // bf16 [16 pos][72]   (64 ch + 8 pad)
#define H2B 1152     // bf16 [16 pos][40]   (32 ch + 8 pad)
#define H3F 1792     // fp32 [16 pos][20]   (16 ch + 4 pad)  (ushort offset; /2 floats)

// Process one 16-position tile: conv0/1/2 via bf16 MFMA (frag-packed B from
// global ws, L2-resident), wave-private LDS round-trip for the C->A relayout,
// VALU tail (redundant per quad), 8x8 upsample store (quad q -> rows 2q,2q+1).
__device__ __forceinline__ void process_tile(
    const float* __restrict__ xr, int bm, int hwm, int q, int n, int lane,
    ushort_t* __restrict__ hb, const ushort_t* __restrict__ wsb,
    const float* __restrict__ b0, const float* __restrict__ b1,
    const float* __restrict__ b2, const float* __restrict__ b3,
    const float* __restrict__ w3, const float* __restrict__ w4,
    const float* __restrict__ b4,
    const float* __restrict__ wc, const float* __restrict__ bc,
    float* __restrict__ out)
{
    // ---- pack A fragments (v_cvt_pk_bf16_f32) ----
    bf8 A[4];
#pragma unroll
    for (int kk = 0; kk < 4; ++kk) {
        bf8 a;
#pragma unroll
        for (int j = 0; j < 8; j += 2) {
            __hip_bfloat162 p = __float22bfloat162_rn(
                make_float2(xr[kk * 8 + j], xr[kk * 8 + j + 1]));
            union { __hip_bfloat162 b; short s[2]; } u; u.b = p;
            a[j] = u.s[0]; a[j + 1] = u.s[1];
        }
        A[kk] = a;
    }

    // ---- conv0: 128 -> 64, 4 N-tiles x 4 K-steps = 16 MFMA ----
    f4 acc[4];
#pragma unroll
    for (int t = 0; t < 4; ++t) {
        const float bb = b0[t * 16 + n];
        acc[t] = (f4){bb, bb, bb, bb};
    }
#pragma unroll
    for (int t = 0; t < 4; ++t) {
        bf8 B[4];
#pragma unroll
        for (int kk = 0; kk < 4; ++kk)
            B[kk] = *(const bf8*)(wsb + F0 + (t * 4 + kk) * 512 + lane * 8);
#pragma unroll
        for (int kk = 0; kk < 4; ++kk)
            acc[t] = __builtin_amdgcn_mfma_f32_16x16x32_bf16(A[kk], B[kk], acc[t], 0, 0, 0);
    }

    // ELU, write C-layout (pos=4q+r, out=16t+n) -> h1[pos][out] bf16
#pragma unroll
    for (int t = 0; t < 4; ++t)
#pragma unroll
        for (int r = 0; r < 4; ++r)
            hb[H1B + (q * 4 + r) * 72 + t * 16 + n] = f2bf(eluf(acc[t][r]));

    // ---- conv1: 64 -> 32, 2 N-tiles x 2 K-steps ----
    bf8 A1[2];
#pragma unroll
    for (int kk = 0; kk < 2; ++kk)
        A1[kk] = *(const bf8*)(hb + H1B + n * 72 + kk * 32 + q * 8);
    f4 acc1[2];
#pragma unroll
    for (int t = 0; t < 2; ++t) {
        const float bb = b1[t * 16 + n];
        acc1[t] = (f4){bb, bb, bb, bb};
    }
#pragma unroll
    for (int t = 0; t < 2; ++t)
#pragma unroll
        for (int kk = 0; kk < 2; ++kk) {
            bf8 B = *(const bf8*)(wsb + F1 + (t * 2 + kk) * 512 + lane * 8);
            acc1[t] = __builtin_amdgcn_mfma_f32_16x16x32_bf16(A1[kk], B, acc1[t], 0, 0, 0);
        }
#pragma unroll
    for (int t = 0; t < 2; ++t)
#pragma unroll
        for (int r = 0; r < 4; ++r)
            hb[H2B + (q * 4 + r) * 40 + t * 16 + n] = f2bf(eluf(acc1[t][r]));

    // ---- conv2: 32 -> 16, single MFMA ----
    bf8 A2 = *(const bf8*)(hb + H2B + n * 40 + q * 8);
    bf8 B2 = *(const bf8*)(wsb + F2 + lane * 8);
    const float bb2 = b2[n];
    f4 acc2 = (f4){bb2, bb2, bb2, bb2};
    acc2 = __builtin_amdgcn_mfma_f32_16x16x32_bf16(A2, B2, acc2, 0, 0, 0);
    float* h3f = (float*)(hb + H3F);
#pragma unroll
    for (int r = 0; r < 4; ++r)
        h3f[(q * 4 + r) * 20 + n] = eluf(acc2[r]);

    // ---- tail: lane handles pos=n (redundant across quads, broadcast reads) ----
    float h3[16];
#pragma unroll
    for (int i = 0; i < 4; ++i) {
        f4 v = *(const f4*)(h3f + n * 20 + i * 4);
        h3[4 * i + 0] = v[0]; h3[4 * i + 1] = v[1];
        h3[4 * i + 2] = v[2]; h3[4 * i + 3] = v[3];
    }

    float h4v[8];
#pragma unroll
    for (int o = 0; o < 8; ++o) {
        float a = b3[o];                              // uniform -> s_load
#pragma unroll
        for (int c = 0; c < 16; ++c) a = fmaf(h3[c], w3[o * 16 + c], a);
        h4v[o] = eluf(a);
    }
    float h5v[4];
#pragma unroll
    for (int o = 0; o < 4; ++o) {
        float a = b4[o];
#pragma unroll
        for (int c = 0; c < 8; ++c) a = fmaf(h4v[c], w4[o * 8 + c], a);
        h5v[o] = a;                                   // no activation
    }
    float y0 = bc[0], y1 = bc[1], y2 = bc[2];
#pragma unroll
    for (int c = 0; c < 4; ++c) {
        y0 = fmaf(h5v[c], wc[0 * 4 + c], y0);
        y1 = fmaf(h5v[c], wc[1 * 4 + c], y1);
        y2 = fmaf(h5v[c], wc[2 * 4 + c], y2);
    }

    const float theta = sigmoidf(y0) * (PI_F / 6.0f);
    const float phi   = sigmoidf(y1) * (PI_F * 2.0f);
    const float dist  = sigmoidf(y2) * 81.0f;
    const float st = __sinf(theta), ct = __cosf(theta);
    const float sp = __sinf(phi),   cp = __cosf(phi);
    float nx = st * cp, ny = st * sp, nz = ct;
    const float inv = rsqrtf(fmaxf(nx * nx + ny * ny + nz * nz, 1e-24f));
    nx *= inv; ny *= inv; nz *= inv;

    // ---- 8x8 upsample: quad q writes rows 2q, 2q+1 of its position ----
    const int hh = hwm / WW;
    const int wp = hwm - hh * WW;
    float* op = out + ((size_t)bm * HOUT + (size_t)hh * SC) * WOUT + (size_t)wp * SC;

    float nxu[8];
#pragma unroll
    for (int j = 0; j < 8; ++j) nxu[j] = nx * ((j - 3.5f) * 0.125f);

#pragma unroll
    for (int ii = 0; ii < 2; ++ii) {
        const int i = q * 2 + ii;
        const float den0 = fmaf(ny, (i - 3.5f) * 0.125f, nz);
        float d[8];
#pragma unroll
        for (int j = 0; j < 8; ++j)
            d[j] = dist * __builtin_amdgcn_rcpf(den0 + nxu[j]);
        float* row = op + (size_t)i * WOUT;           // 32B-aligned
        *reinterpret_cast<float4*>(row)     = make_float4(d[0], d[1], d[2], d[3]);
        *reinterpret_cast<float4*>(row + 4) = make_float4(d[4], d[5], d[6], d[7]);
    }
}

// One wave = 32 positions (2 x 16-pos tiles), software-pipelined: both tiles'
// x loads issued up front, tile1's loads stay in flight through tile0's
// compute/tail/store (compiler emits partial vmcnt waits). B-frags get 2x
// reuse, half the block prologues. No barriers anywhere.
__global__ __launch_bounds__(256, 3)
void lpg_mfma(const float* __restrict__ x, const ushort_t* __restrict__ wsb,
              const float* __restrict__ b0, const float* __restrict__ b1,
              const float* __restrict__ b2, const float* __restrict__ b3,
              const float* __restrict__ w3, const float* __restrict__ w4,
              const float* __restrict__ b4,
              const float* __restrict__ wc, const float* __restrict__ bc,
              float* __restrict__ out) {
    __shared__ __align__(16) ushort_t hbuf[4][2432];

    const int tid  = (int)threadIdx.x;
    const int lane = tid & 63;
    const int wid  = tid >> 6;
    const int q    = lane >> 4;          // quad 0..3
    const int n    = lane & 15;          // position-within-tile / out-channel idx

    const int pm0 = blockIdx.x * 128 + wid * 32 + n;   // tile0 position
    const int pm1 = pm0 + 16;                           // tile1 position
    const int bm0 = pm0 / HW, hw0 = pm0 - bm0 * HW;
    const int bm1 = pm1 / HW, hw1 = pm1 - bm1 * HW;

    // ---- issue BOTH tiles' x loads up front ----
    // A[m=n][k=kk*32+q*8+j]: per load instr, 4 quads x 16 consecutive pos = 4x64B segs
    const float* xb0 = x + (size_t)bm0 * (C0 * HW) + hw0;
    const float* xb1 = x + (size_t)bm1 * (C0 * HW) + hw1;
    float xr0[32], xr1[32];
#pragma unroll
    for (int kk = 0; kk < 4; ++kk)
#pragma unroll
        for (int j = 0; j < 8; ++j)
            xr0[kk * 8 + j] = xb0[(kk * 32 + q * 8 + j) * HW];
#pragma unroll
    for (int kk = 0; kk < 4; ++kk)
#pragma unroll
        for (int j = 0; j < 8; ++j)
            xr1[kk * 8 + j] = xb1[(kk * 32 + q * 8 + j) * HW];

    ushort_t* hb = &hbuf[wid][0];
    process_tile(xr0, bm0, hw0, q, n, lane, hb, wsb,
                 b0, b1, b2, b3, w3, w4, b4, wc, bc, out);
    process_tile(xr1, bm1, hw1, q, n, lane, hb, wsb,
                 b0, b1, b2, b3, w3, w4, b4, wc, bc, out);
}

extern "C" void kernel_launch(void* const* d_in, const int* in_sizes, int n_in,
                              void* d_out, int out_size, void* d_ws, size_t ws_size,
                              hipStream_t stream) {
    const float* x  = (const float*)d_in[0];
    const float* w0 = (const float*)d_in[1];  const float* b0 = (const float*)d_in[2];
    const float* w1 = (const float*)d_in[3];  const float* b1 = (const float*)d_in[4];
    const float* w2 = (const float*)d_in[5];  const float* b2 = (const float*)d_in[6];
    const float* w3 = (const float*)d_in[7];  const float* b3 = (const float*)d_in[8];
    const float* w4 = (const float*)d_in[9];  const float* b4 = (const float*)d_in[10];
    const float* wc = (const float*)d_in[11]; const float* bc = (const float*)d_in[12];
    ushort_t* ws = (ushort_t*)d_ws;            // 21,504 B used
    float* out = (float*)d_out;

    hipLaunchKernelGGL(prep_w, dim3((NWT + 255) / 256), dim3(256), 0, stream,
                       w0, w1, w2, ws);
    hipLaunchKernelGGL(lpg_mfma, dim3(NPOS / 128), dim3(256), 0, stream,
                       x, ws, b0, b1, b2, b3, w3, w4, b4, wc, bc, out);
}